// Round 1
// baseline (9087.868 us; speedup 1.0000x reference)
//
#include <hip/hip_runtime.h>

#define SEQ 512
#define TOT 514                 // 512 scan steps + 2 autoregressive steps
#define BH  65536               // 64 rows * 1024 hidden = elems per h/x timestep
#define NBUF (TOT + 1)          // h buffers: h[0]=hx0, h[t+1] = output of step t

typedef _Float16 f16x8 __attribute__((ext_vector_type(8)));
typedef float f32x4 __attribute__((ext_vector_type(4)));

__device__ __forceinline__ unsigned short f2h_bits(float f) {
  union { _Float16 h; unsigned short s; } u; u.h = (_Float16)f; return u.s;
}

// Convert x [512,64,1024] and hx0 [64,1024] fp32 -> f16 once, up front.
__global__ void cvt_kernel(const float* __restrict__ x, const float* __restrict__ hx0,
                           unsigned short* __restrict__ X16, unsigned short* __restrict__ H0) {
  const long long n4x = (long long)SEQ * BH / 4;
  const long long n4h = BH / 4;
  const long long stride = (long long)gridDim.x * blockDim.x;
  for (long long i = (long long)blockIdx.x * blockDim.x + threadIdx.x;
       i < n4x + n4h; i += stride) {
    const float4* src; unsigned short* dst; long long j;
    if (i < n4x) { src = (const float4*)x;   dst = X16; j = i; }
    else         { src = (const float4*)hx0; dst = H0;  j = i - n4x; }
    float4 v = src[j];
    union { unsigned short s[4]; unsigned long long u; } pk;
    pk.s[0] = f2h_bits(v.x); pk.s[1] = f2h_bits(v.y);
    pk.s[2] = f2h_bits(v.z); pk.s[3] = f2h_bits(v.w);
    *(unsigned long long*)(dst + 4 * j) = pk.u;
  }
}

// Persistent LSTM kernel.
// Grid = 256 blocks (1 per CU, VGPR-forced), 256 threads (4 waves).
// block -> (batch quarter q = blockIdx>>6: rows [16q,16q+16), unit slice: 16 hidden
// units at ub=(blockIdx&63)*16, i.e. 64 gate columns {g*1024+ub+u}).
// Wave w holds B-fragments for K-quarter w of combined K=2048 ([x;h] vs [W_ih;W_hh])
// in 256 VGPRs, resident across all 514 steps.
__global__ __launch_bounds__(256, 1)
void lstm_kernel(const float* __restrict__ cx0,
                 const float* __restrict__ W_ih, const float* __restrict__ W_hh,
                 const float* __restrict__ b_ih, const float* __restrict__ b_hh,
                 const unsigned short* __restrict__ X16,
                 unsigned short* __restrict__ H16,
                 int* __restrict__ flags,
                 float* __restrict__ out) {
  __shared__ float red[4][16][68];          // [wave][m][n], pad 64->68: 2-way banks only
  __shared__ unsigned short hst[16][16];    // h f16 staging for packed stores

  const int tid  = threadIdx.x;
  const int wave = tid >> 6;
  const int lane = tid & 63;
  const int u16v = lane & 15;               // MFMA m (A row) / n (B col) index
  const int q4   = lane >> 4;               // MFMA quad
  const int q    = blockIdx.x >> 6;         // batch quarter
  const int ub   = (blockIdx.x & 63) * 16;  // hidden-unit base

  // ---------- stage weight B-fragments into registers (fp32 -> f16) ----------
  // B layout for mfma_f32_16x16x32_f16: B[k = q4*8+j][n = lane&15], k contiguous,
  // which matches W[col][k] row-major exactly.
  f16x8 bf[4][16];                          // [gate][k-iter] : 256 VGPRs
  {
    const float* wsrc = (wave < 2) ? W_ih : W_hh;
    const int kb = (wave & 1) * 512;        // this wave's K-quarter within its matrix
#pragma unroll
    for (int nt = 0; nt < 4; ++nt) {        // nt == gate (i,f,g,o)
      const float* wr = wsrc + (size_t)((nt << 10) + ub + u16v) * 1024 + kb + q4 * 8;
#pragma unroll
      for (int i = 0; i < 16; ++i) {
        float4 w0 = *(const float4*)(wr + i * 32);
        float4 w1 = *(const float4*)(wr + i * 32 + 4);
        f16x8 b;
        b[0] = (_Float16)w0.x; b[1] = (_Float16)w0.y; b[2] = (_Float16)w0.z; b[3] = (_Float16)w0.w;
        b[4] = (_Float16)w1.x; b[5] = (_Float16)w1.y; b[6] = (_Float16)w1.z; b[7] = (_Float16)w1.w;
        bf[nt][i] = b;
      }
    }
  }

  // ---------- per-thread recurrent state (elementwise mapping) ----------
  const int er = tid >> 4, eu = tid & 15;   // (row-in-quarter, unit-in-slice)
  const int rge = q * 16 + er;              // global batch row
  float c = cx0[rge * 1024 + ub + eu];
  const float bi  = b_ih[       ub + eu] + b_hh[       ub + eu];
  const float bfg = b_ih[1024 + ub + eu] + b_hh[1024 + ub + eu];
  const float bg  = b_ih[2048 + ub + eu] + b_hh[2048 + ub + eu];
  const float bo  = b_ih[3072 + ub + eu] + b_hh[3072 + ub + eu];

  // A-fragment address base: A[m = lane&15][k = q4*8+j], row-major [64,1024] f16
  const size_t abase = (size_t)(q * 16 + u16v) * 1024 + (wave & 1) * 512 + q4 * 8;

  for (int t = 0; t < TOT; ++t) {
    // Wait until all 64 blocks of this quarter published h[t] (skip t=0: cvt kernel).
    if (t > 0 && tid == 0) {
      int* f = &flags[(t - 1) * 4 + q];
      while (__hip_atomic_load(f, __ATOMIC_RELAXED, __HIP_MEMORY_SCOPE_AGENT) < 64)
        __builtin_amdgcn_s_sleep(1);
      (void)__hip_atomic_load(f, __ATOMIC_ACQUIRE, __HIP_MEMORY_SCOPE_AGENT);
    }
    __syncthreads();

    const unsigned short* hsrc = H16 + (size_t)t * BH;
    const unsigned short* asrc = (wave < 2 && t < SEQ) ? (X16 + (size_t)t * BH) : hsrc;
    // h buffers are cross-XCD producer data -> read via agent-scope (LLC) atomics.
    const bool atom = (wave >= 2) || (t >= SEQ);

    f16x8 afr[16];
#pragma unroll
    for (int i = 0; i < 16; ++i) {
      const unsigned short* p = asrc + abase + i * 32;
      if (atom) {
        union { unsigned long long u[2]; f16x8 v; } cv;
        cv.u[0] = __hip_atomic_load((unsigned long long*)p,       __ATOMIC_RELAXED, __HIP_MEMORY_SCOPE_AGENT);
        cv.u[1] = __hip_atomic_load((unsigned long long*)(p + 4), __ATOMIC_RELAXED, __HIP_MEMORY_SCOPE_AGENT);
        afr[i] = cv.v;
      } else {
        afr[i] = *(const f16x8*)p;
      }
    }

    f32x4 a0 = {0.f, 0.f, 0.f, 0.f}, a1 = a0, a2 = a0, a3 = a0;
#pragma unroll
    for (int i = 0; i < 16; ++i) {
      a0 = __builtin_amdgcn_mfma_f32_16x16x32_f16(afr[i], bf[0][i], a0, 0, 0, 0);
      a1 = __builtin_amdgcn_mfma_f32_16x16x32_f16(afr[i], bf[1][i], a1, 0, 0, 0);
      a2 = __builtin_amdgcn_mfma_f32_16x16x32_f16(afr[i], bf[2][i], a2, 0, 0, 0);
      a3 = __builtin_amdgcn_mfma_f32_16x16x32_f16(afr[i], bf[3][i], a3, 0, 0, 0);
    }

    // C/D layout: col = lane&15, row = q4*4 + reg. Write partials for reduction.
#pragma unroll
    for (int r = 0; r < 4; ++r) {
      red[wave][q4 * 4 + r][     u16v] = a0[r];
      red[wave][q4 * 4 + r][16 + u16v] = a1[r];
      red[wave][q4 * 4 + r][32 + u16v] = a2[r];
      red[wave][q4 * 4 + r][48 + u16v] = a3[r];
    }
    __syncthreads();

    // Reduce 4 K-partials + bias, then LSTM cell math in fp32.
    float gi = bi, gf = bfg, gg = bg, go = bo;
#pragma unroll
    for (int w2 = 0; w2 < 4; ++w2) {
      gi += red[w2][er][     eu];
      gf += red[w2][er][16 + eu];
      gg += red[w2][er][32 + eu];
      go += red[w2][er][48 + eu];
    }
    float si = 1.f / (1.f + __expf(-gi));
    float sf = 1.f / (1.f + __expf(-gf));
    float so = 1.f / (1.f + __expf(-go));
    c = sf * c + si * tanhf(gg);
    float h = so * tanhf(c);
    hst[er][eu] = f2h_bits(h);
    if (t >= SEQ) out[(size_t)(t - SEQ) * BH + rge * 1024 + ub + eu] = h;
    __syncthreads();

    // Publish h[t+1] slice: packed u32 agent-scope stores (write-through to LLC).
    if (tid < 128) {
      int r2 = tid >> 3, p2 = tid & 7;
      unsigned int val = *(unsigned int*)&hst[r2][p2 * 2];
      unsigned short* dst = H16 + (size_t)(t + 1) * BH +
                            (size_t)(q * 16 + r2) * 1024 + ub + p2 * 2;
      __hip_atomic_store((unsigned int*)dst, val, __ATOMIC_RELAXED, __HIP_MEMORY_SCOPE_AGENT);
    }
    __syncthreads();   // drains vmcnt in every wave before the flag is raised
    if (tid == 0)
      __hip_atomic_fetch_add(&flags[t * 4 + q], 1, __ATOMIC_RELEASE, __HIP_MEMORY_SCOPE_AGENT);
  }
}

extern "C" void kernel_launch(void* const* d_in, const int* in_sizes, int n_in,
                              void* d_out, int out_size, void* d_ws, size_t ws_size,
                              hipStream_t stream) {
  const float* x    = (const float*)d_in[0];
  const float* hx0  = (const float*)d_in[1];
  const float* cx0  = (const float*)d_in[2];
  const float* W_ih = (const float*)d_in[3];
  const float* W_hh = (const float*)d_in[4];
  const float* b_ih = (const float*)d_in[5];
  const float* b_hh = (const float*)d_in[6];

  // Workspace layout: X16 (67.1 MB) | H16 (67.5 MB) | flags (8.2 KB)  ~= 135 MB
  unsigned short* X16 = (unsigned short*)d_ws;
  unsigned short* H16 = X16 + (size_t)SEQ * BH;
  int* flags = (int*)(H16 + (size_t)NBUF * BH);

  hipMemsetAsync(flags, 0, (size_t)TOT * 4 * sizeof(int), stream);
  cvt_kernel<<<1024, 256, 0, stream>>>(x, hx0, X16, H16);
  lstm_kernel<<<256, 256, 0, stream>>>(cx0, W_ih, W_hh, b_ih, b_hh,
                                       X16, H16, flags, (float*)d_out);
}

// Round 2
// 5062.790 us; speedup vs baseline: 1.7950x; 1.7950x over previous
//
#include <hip/hip_runtime.h>

#define SEQ 512
#define TOT 514                 // 512 scan steps + 2 autoregressive steps
#define BH  65536               // 64 rows * 1024 hidden = elems per h/x timestep
#define NBUF (TOT + 1)          // h buffers: h[0]=hx0, h[t+1] = output of step t

typedef _Float16 f16x8 __attribute__((ext_vector_type(8)));
typedef float f32x4 __attribute__((ext_vector_type(4)));

__device__ __forceinline__ unsigned short f2h_bits(float f) {
  union { _Float16 h; unsigned short s; } u; u.h = (_Float16)f; return u.s;
}

// Convert x [512,64,1024] and hx0 [64,1024] fp32 -> f16 once, up front.
__global__ void cvt_kernel(const float* __restrict__ x, const float* __restrict__ hx0,
                           unsigned short* __restrict__ X16, unsigned short* __restrict__ H0) {
  const long long n4x = (long long)SEQ * BH / 4;
  const long long n4h = BH / 4;
  const long long stride = (long long)gridDim.x * blockDim.x;
  for (long long i = (long long)blockIdx.x * blockDim.x + threadIdx.x;
       i < n4x + n4h; i += stride) {
    const float4* src; unsigned short* dst; long long j;
    if (i < n4x) { src = (const float4*)x;   dst = X16; j = i; }
    else         { src = (const float4*)hx0; dst = H0;  j = i - n4x; }
    float4 v = src[j];
    union { unsigned short s[4]; unsigned long long u; } pk;
    pk.s[0] = f2h_bits(v.x); pk.s[1] = f2h_bits(v.y);
    pk.s[2] = f2h_bits(v.z); pk.s[3] = f2h_bits(v.w);
    *(unsigned long long*)(dst + 4 * j) = pk.u;
  }
}

// Persistent LSTM kernel. Grid = 256 blocks (1/CU, VGPR-forced), 256 threads.
// block -> (batch quarter q = blockIdx>>6: rows [16q,16q+16), unit slice ub).
// Wave w owns K-slice [w*256, w*256+256) of BOTH W_ih and W_hh, fragments
// register/AGPR-resident across all 514 steps. x-side work is issued BEFORE
// the flag poll (off the recurrent critical path).
__global__ __launch_bounds__(256, 1)
void lstm_kernel(const float* __restrict__ cx0,
                 const float* __restrict__ W_ih, const float* __restrict__ W_hh,
                 const float* __restrict__ b_ih, const float* __restrict__ b_hh,
                 const unsigned short* __restrict__ X16,
                 unsigned short* __restrict__ H16,
                 int* __restrict__ flags,
                 float* __restrict__ out) {
  __shared__ float red[4][16][68];          // [wave][m][n], pad 64->68
  __shared__ unsigned short hst[16][16];    // h f16 staging for packed stores

  const int tid  = threadIdx.x;
  const int wave = tid >> 6;
  const int lane = tid & 63;
  const int u16v = lane & 15;               // MFMA m (A row) / n (B col) index
  const int q4   = lane >> 4;               // MFMA quad
  const int q    = blockIdx.x >> 6;         // batch quarter
  const int s    = blockIdx.x & 63;         // unit-slice index
  const int ub   = s * 16;                  // hidden-unit base
  const int kb   = wave * 256;              // this wave's K-slice (in both matrices)

  // ---------- stage weight B-fragments into registers (fp32 -> f16) ----------
  // B layout for mfma_f32_16x16x32_f16: B[k = q4*8+j][n = lane&15]; row-major
  // W[col][k] matches k-contiguity exactly.
  f16x8 bfx[4][8], bfh[4][8];               // [gate][k-iter] : 128+128 regs
#pragma unroll
  for (int g = 0; g < 4; ++g) {
    const float* wi = W_ih + (size_t)((g << 10) + ub + u16v) * 1024 + kb + q4 * 8;
    const float* wh = W_hh + (size_t)((g << 10) + ub + u16v) * 1024 + kb + q4 * 8;
#pragma unroll
    for (int i = 0; i < 8; ++i) {
      float4 x0 = *(const float4*)(wi + i * 32);
      float4 x1 = *(const float4*)(wi + i * 32 + 4);
      float4 h0 = *(const float4*)(wh + i * 32);
      float4 h1 = *(const float4*)(wh + i * 32 + 4);
      f16x8 bx, bh;
      bx[0] = (_Float16)x0.x; bx[1] = (_Float16)x0.y; bx[2] = (_Float16)x0.z; bx[3] = (_Float16)x0.w;
      bx[4] = (_Float16)x1.x; bx[5] = (_Float16)x1.y; bx[6] = (_Float16)x1.z; bx[7] = (_Float16)x1.w;
      bh[0] = (_Float16)h0.x; bh[1] = (_Float16)h0.y; bh[2] = (_Float16)h0.z; bh[3] = (_Float16)h0.w;
      bh[4] = (_Float16)h1.x; bh[5] = (_Float16)h1.y; bh[6] = (_Float16)h1.z; bh[7] = (_Float16)h1.w;
      bfx[g][i] = bx; bfh[g][i] = bh;
    }
  }

  // ---------- per-thread recurrent state (elementwise mapping) ----------
  const int er = tid >> 4, eu = tid & 15;   // (row-in-quarter, unit-in-slice)
  const int rge = q * 16 + er;              // global batch row
  float c = cx0[rge * 1024 + ub + eu];
  const float bi  = b_ih[       ub + eu] + b_hh[       ub + eu];
  const float bfg = b_ih[1024 + ub + eu] + b_hh[1024 + ub + eu];
  const float bg  = b_ih[2048 + ub + eu] + b_hh[2048 + ub + eu];
  const float bo  = b_ih[3072 + ub + eu] + b_hh[3072 + ub + eu];

  // A-fragment base: A[m = lane&15][k = q4*8+j], row-major [64,1024] f16
  const size_t abase = (size_t)(q * 16 + u16v) * 1024 + kb + q4 * 8;

  for (int t = 0; t < TOT; ++t) {
    f32x4 a0 = {0.f, 0.f, 0.f, 0.f}, a1 = a0, a2 = a0, a3 = a0;

    // ===== x-phase: no dependency on h[t]; runs before the poll/acquire =====
    if (t < SEQ) {
      const unsigned short* xs = X16 + (size_t)t * BH + abase;
      f16x8 xf[8];
#pragma unroll
      for (int i = 0; i < 8; ++i) xf[i] = *(const f16x8*)(xs + i * 32);
#pragma unroll
      for (int i = 0; i < 8; ++i) {
        a0 = __builtin_amdgcn_mfma_f32_16x16x32_f16(xf[i], bfx[0][i], a0, 0, 0, 0);
        a1 = __builtin_amdgcn_mfma_f32_16x16x32_f16(xf[i], bfx[1][i], a1, 0, 0, 0);
        a2 = __builtin_amdgcn_mfma_f32_16x16x32_f16(xf[i], bfx[2][i], a2, 0, 0, 0);
        a3 = __builtin_amdgcn_mfma_f32_16x16x32_f16(xf[i], bfx[3][i], a3, 0, 0, 0);
      }
    }

    // ===== wait for all 64 peer blocks of this quarter to publish h[t] =====
    // Per-block flags on private 128B lines: parallel release-stores, 64-lane poll.
    if (wave == 0) {
      const int* fp = flags + (size_t)(q * 64 + lane) * 32;
      while (true) {
        int v = __hip_atomic_load(fp, __ATOMIC_RELAXED, __HIP_MEMORY_SCOPE_AGENT);
        if (__all(v >= t)) break;
        __builtin_amdgcn_s_sleep(1);
      }
      (void)__hip_atomic_load(fp, __ATOMIC_ACQUIRE, __HIP_MEMORY_SCOPE_AGENT);
    }
    __syncthreads();

    // ===== h-phase: agent-scope loads (cross-XCD producer data) =====
    const unsigned short* hs = H16 + (size_t)t * BH + abase;
    f16x8 hf[8];
#pragma unroll
    for (int i = 0; i < 8; ++i) {
      const unsigned short* p = hs + i * 32;
      union { unsigned long long u[2]; f16x8 v; } cv;
      cv.u[0] = __hip_atomic_load((unsigned long long*)p,       __ATOMIC_RELAXED, __HIP_MEMORY_SCOPE_AGENT);
      cv.u[1] = __hip_atomic_load((unsigned long long*)(p + 4), __ATOMIC_RELAXED, __HIP_MEMORY_SCOPE_AGENT);
      hf[i] = cv.v;
    }
#pragma unroll
    for (int i = 0; i < 8; ++i) {
      a0 = __builtin_amdgcn_mfma_f32_16x16x32_f16(hf[i], bfh[0][i], a0, 0, 0, 0);
      a1 = __builtin_amdgcn_mfma_f32_16x16x32_f16(hf[i], bfh[1][i], a1, 0, 0, 0);
      a2 = __builtin_amdgcn_mfma_f32_16x16x32_f16(hf[i], bfh[2][i], a2, 0, 0, 0);
      a3 = __builtin_amdgcn_mfma_f32_16x16x32_f16(hf[i], bfh[3][i], a3, 0, 0, 0);
    }
    if (t >= SEQ) {  // autoregressive: x_t := h[t], add the W_ih side too
#pragma unroll
      for (int i = 0; i < 8; ++i) {
        a0 = __builtin_amdgcn_mfma_f32_16x16x32_f16(hf[i], bfx[0][i], a0, 0, 0, 0);
        a1 = __builtin_amdgcn_mfma_f32_16x16x32_f16(hf[i], bfx[1][i], a1, 0, 0, 0);
        a2 = __builtin_amdgcn_mfma_f32_16x16x32_f16(hf[i], bfx[2][i], a2, 0, 0, 0);
        a3 = __builtin_amdgcn_mfma_f32_16x16x32_f16(hf[i], bfx[3][i], a3, 0, 0, 0);
      }
    }

    // C/D layout: col = lane&15, row = q4*4 + reg. Stage partials for reduction.
#pragma unroll
    for (int r = 0; r < 4; ++r) {
      red[wave][q4 * 4 + r][     u16v] = a0[r];
      red[wave][q4 * 4 + r][16 + u16v] = a1[r];
      red[wave][q4 * 4 + r][32 + u16v] = a2[r];
      red[wave][q4 * 4 + r][48 + u16v] = a3[r];
    }
    __syncthreads();

    // Reduce 4 K-partials + bias, then LSTM cell math in fp32.
    float gi = bi, gf = bfg, gg = bg, go = bo;
#pragma unroll
    for (int w2 = 0; w2 < 4; ++w2) {
      gi += red[w2][er][     eu];
      gf += red[w2][er][16 + eu];
      gg += red[w2][er][32 + eu];
      go += red[w2][er][48 + eu];
    }
    float si = 1.f / (1.f + __expf(-gi));
    float sf = 1.f / (1.f + __expf(-gf));
    float so = 1.f / (1.f + __expf(-go));
    c = sf * c + si * tanhf(gg);
    float h = so * tanhf(c);
    hst[er][eu] = f2h_bits(h);
    if (t >= SEQ) out[(size_t)(t - SEQ) * BH + rge * 1024 + ub + eu] = h;
    __syncthreads();   // hst visible to wave 0

    // Publish h[t+1] slice (wave 0: 64 packed u64 agent stores), then raise our
    // flag. Release in the SAME wave orders all 64 lanes' stores (vmcnt drain).
    if (wave == 0) {
      const int r2 = lane >> 2, c2 = (lane & 3) * 4;
      unsigned long long val = *(unsigned long long*)&hst[r2][c2];
      unsigned short* dst = H16 + (size_t)(t + 1) * BH +
                            (size_t)(q * 16 + r2) * 1024 + ub + c2;
      __hip_atomic_store((unsigned long long*)dst, val, __ATOMIC_RELAXED, __HIP_MEMORY_SCOPE_AGENT);
      if (lane == 0)
        __hip_atomic_store(flags + (size_t)(q * 64 + s) * 32, t + 1,
                           __ATOMIC_RELEASE, __HIP_MEMORY_SCOPE_AGENT);
    }
  }
}

extern "C" void kernel_launch(void* const* d_in, const int* in_sizes, int n_in,
                              void* d_out, int out_size, void* d_ws, size_t ws_size,
                              hipStream_t stream) {
  const float* x    = (const float*)d_in[0];
  const float* hx0  = (const float*)d_in[1];
  const float* cx0  = (const float*)d_in[2];
  const float* W_ih = (const float*)d_in[3];
  const float* W_hh = (const float*)d_in[4];
  const float* b_ih = (const float*)d_in[5];
  const float* b_hh = (const float*)d_in[6];

  // Workspace: X16 (67.1 MB) | H16 (67.5 MB) | flags (32 KB)  ~= 135 MB
  unsigned short* X16 = (unsigned short*)d_ws;
  unsigned short* H16 = X16 + (size_t)SEQ * BH;
  int* flags = (int*)(H16 + (size_t)NBUF * BH);

  hipMemsetAsync(flags, 0, (size_t)256 * 32 * sizeof(int), stream);
  cvt_kernel<<<1024, 256, 0, stream>>>(x, hx0, X16, H16);
  lstm_kernel<<<256, 256, 0, stream>>>(cx0, W_ih, W_hh, b_ih, b_hh,
                                       X16, H16, flags, (float*)d_out);
}

// Round 3
// 4157.590 us; speedup vs baseline: 2.1859x; 1.2177x over previous
//
#include <hip/hip_runtime.h>

#define SEQ 512
#define TOT 514                 // 512 scan steps + 2 autoregressive steps
#define BH  65536               // 64 rows * 1024 hidden = elems per h/x timestep
#define NBUF (TOT + 1)          // h buffers: h[0]=hx0, h[t+1] = output of step t

typedef _Float16 f16x8 __attribute__((ext_vector_type(8)));
typedef float f32x4 __attribute__((ext_vector_type(4)));

__device__ __forceinline__ unsigned short f2h_bits(float f) {
  union { _Float16 h; unsigned short s; } u; u.h = (_Float16)f; return u.s;
}

__device__ __forceinline__ float fast_sigmoid(float x) {
  return 1.f / (1.f + __expf(-x));
}
__device__ __forceinline__ float fast_tanh(float x) {
  float e = __expf(-2.f * fabsf(x));
  float r = (1.f - e) / (1.f + e);
  return copysignf(r, x);
}

// Convert x [512,64,1024] fp32 -> f16 (row-major) and hx0 -> blocked H layout
// H[t][q][s][r:16][u:16] (each producer block's slice = 512B contiguous).
__global__ void cvt_kernel(const float* __restrict__ x, const float* __restrict__ hx0,
                           unsigned short* __restrict__ X16, unsigned short* __restrict__ H0) {
  const long long n4x = (long long)SEQ * BH / 4;
  const long long n4h = BH / 4;
  const long long stride = (long long)gridDim.x * blockDim.x;
  for (long long i = (long long)blockIdx.x * blockDim.x + threadIdx.x;
       i < n4x + n4h; i += stride) {
    const float* src; unsigned short* dst;
    if (i < n4x) {
      src = x + 4 * i; dst = X16 + 4 * i;
    } else {
      long long e = (i - n4x) * 4;         // blocked linear offset
      int u0 = e & 15, r = (e >> 4) & 15, sl = (e >> 8) & 63, qq = (int)(e >> 14);
      src = hx0 + (qq * 16 + r) * 1024 + sl * 16 + u0;
      dst = H0 + e;
    }
    float4 v = *(const float4*)src;
    union { unsigned short s[4]; unsigned long long u; } pk;
    pk.s[0] = f2h_bits(v.x); pk.s[1] = f2h_bits(v.y);
    pk.s[2] = f2h_bits(v.z); pk.s[3] = f2h_bits(v.w);
    *(unsigned long long*)dst = pk.u;
  }
}

// Persistent LSTM kernel. Grid = 256 blocks (1/CU), 256 threads (4 waves).
// block -> (batch quarter q: rows [16q,16q+16), unit slice ub = s*16).
// Wave w owns K-slice [w*256,+256) of BOTH W_ih and W_hh, register-resident.
// x-side MFMA issued BEFORE the flag poll (off the recurrent critical path).
// Flags: 64 contiguous u32 per quarter (2 cache lines) -> coalesced polling.
__global__ __launch_bounds__(256, 1)
void lstm_kernel(const float* __restrict__ cx0,
                 const float* __restrict__ W_ih, const float* __restrict__ W_hh,
                 const float* __restrict__ b_ih, const float* __restrict__ b_hh,
                 const unsigned short* __restrict__ X16,
                 unsigned short* __restrict__ H16,
                 int* __restrict__ flags,
                 float* __restrict__ out) {
  __shared__ float red[4][16][68];          // [wave][m][n], pad 64->68
  __shared__ unsigned short hst[16][16];    // h f16 staging for packed publish

  const int tid  = threadIdx.x;
  const int wave = tid >> 6;
  const int lane = tid & 63;
  const int u16v = lane & 15;               // MFMA m (A row) / n (B col) index
  const int q4   = lane >> 4;               // MFMA quad
  const int q    = blockIdx.x >> 6;         // batch quarter
  const int s    = blockIdx.x & 63;         // unit-slice index
  const int ub   = s * 16;                  // hidden-unit base
  const int kb   = wave * 256;              // this wave's K-slice (both matrices)

  // ---------- stage weight B-fragments into registers (fp32 -> f16) ----------
  // B layout for mfma_f32_16x16x32_f16: B[k = q4*8+j][n = lane&15]; row-major
  // W[col][k] matches k-contiguity exactly.
  f16x8 bfx[4][8], bfh[4][8];
#pragma unroll
  for (int g = 0; g < 4; ++g) {
    const float* wi = W_ih + (size_t)((g << 10) + ub + u16v) * 1024 + kb + q4 * 8;
    const float* wh = W_hh + (size_t)((g << 10) + ub + u16v) * 1024 + kb + q4 * 8;
#pragma unroll
    for (int i = 0; i < 8; ++i) {
      float4 x0 = *(const float4*)(wi + i * 32);
      float4 x1 = *(const float4*)(wi + i * 32 + 4);
      float4 h0 = *(const float4*)(wh + i * 32);
      float4 h1 = *(const float4*)(wh + i * 32 + 4);
      f16x8 bx, bh;
      bx[0] = (_Float16)x0.x; bx[1] = (_Float16)x0.y; bx[2] = (_Float16)x0.z; bx[3] = (_Float16)x0.w;
      bx[4] = (_Float16)x1.x; bx[5] = (_Float16)x1.y; bx[6] = (_Float16)x1.z; bx[7] = (_Float16)x1.w;
      bh[0] = (_Float16)h0.x; bh[1] = (_Float16)h0.y; bh[2] = (_Float16)h0.z; bh[3] = (_Float16)h0.w;
      bh[4] = (_Float16)h1.x; bh[5] = (_Float16)h1.y; bh[6] = (_Float16)h1.z; bh[7] = (_Float16)h1.w;
      bfx[g][i] = bx; bfh[g][i] = bh;
    }
  }

  // ---------- per-thread recurrent state (elementwise mapping) ----------
  const int er = tid >> 4, eu = tid & 15;   // (row-in-quarter, unit-in-slice)
  const int rge = q * 16 + er;              // global batch row
  float c = cx0[rge * 1024 + ub + eu];
  const float bi  = b_ih[       ub + eu] + b_hh[       ub + eu];
  const float bfg = b_ih[1024 + ub + eu] + b_hh[1024 + ub + eu];
  const float bg  = b_ih[2048 + ub + eu] + b_hh[2048 + ub + eu];
  const float bo  = b_ih[3072 + ub + eu] + b_hh[3072 + ub + eu];

  // x A-fragment base (row-major [64,1024] f16): A[m=lane&15][k=q4*8+j]
  const size_t xbase = (size_t)(q * 16 + u16v) * 1024 + kb + q4 * 8;
  // h A-fragment base (blocked layout): element offset within a timestep
  const size_t hfrag = ((size_t)(q * 64 + wave * 16 + (q4 >> 1)) << 8)
                       + u16v * 16 + (q4 & 1) * 8;     // + i*512 per k-iter

  for (int t = 0; t < TOT; ++t) {
    f32x4 a0 = {0.f, 0.f, 0.f, 0.f}, a1 = a0, a2 = a0, a3 = a0;

    // ===== x-phase: no dependency on h[t]; runs before the poll/acquire =====
    if (t < SEQ) {
      const unsigned short* xs = X16 + (size_t)t * BH + xbase;
      f16x8 xf[8];
#pragma unroll
      for (int i = 0; i < 8; ++i) xf[i] = *(const f16x8*)(xs + i * 32);
#pragma unroll
      for (int i = 0; i < 8; ++i) {
        a0 = __builtin_amdgcn_mfma_f32_16x16x32_f16(xf[i], bfx[0][i], a0, 0, 0, 0);
        a1 = __builtin_amdgcn_mfma_f32_16x16x32_f16(xf[i], bfx[1][i], a1, 0, 0, 0);
        a2 = __builtin_amdgcn_mfma_f32_16x16x32_f16(xf[i], bfx[2][i], a2, 0, 0, 0);
        a3 = __builtin_amdgcn_mfma_f32_16x16x32_f16(xf[i], bfx[3][i], a3, 0, 0, 0);
      }
    }

    // ===== wait for the 64 peer blocks of this quarter to publish h[t] =====
    // 64 contiguous u32 flags per quarter: one coalesced 256B poll load.
    if (wave == 0) {
      const int* fp = flags + q * 64 + lane;
      while (true) {
        int v = __hip_atomic_load(fp, __ATOMIC_RELAXED, __HIP_MEMORY_SCOPE_AGENT);
        if (__all(v >= t)) break;
        __builtin_amdgcn_s_sleep(1);
      }
      (void)__hip_atomic_load(fp, __ATOMIC_ACQUIRE, __HIP_MEMORY_SCOPE_AGENT);
    }
    __syncthreads();

    // ===== h-phase: agent-scope loads (cross-XCD producer data) =====
    const unsigned short* hs = H16 + (size_t)t * BH + hfrag;
    f16x8 hf[8];
#pragma unroll
    for (int i = 0; i < 8; ++i) {
      const unsigned short* p = hs + i * 512;
      union { unsigned long long u[2]; f16x8 v; } cv;
      cv.u[0] = __hip_atomic_load((unsigned long long*)p,       __ATOMIC_RELAXED, __HIP_MEMORY_SCOPE_AGENT);
      cv.u[1] = __hip_atomic_load((unsigned long long*)(p + 4), __ATOMIC_RELAXED, __HIP_MEMORY_SCOPE_AGENT);
      hf[i] = cv.v;
    }
#pragma unroll
    for (int i = 0; i < 8; ++i) {
      a0 = __builtin_amdgcn_mfma_f32_16x16x32_f16(hf[i], bfh[0][i], a0, 0, 0, 0);
      a1 = __builtin_amdgcn_mfma_f32_16x16x32_f16(hf[i], bfh[1][i], a1, 0, 0, 0);
      a2 = __builtin_amdgcn_mfma_f32_16x16x32_f16(hf[i], bfh[2][i], a2, 0, 0, 0);
      a3 = __builtin_amdgcn_mfma_f32_16x16x32_f16(hf[i], bfh[3][i], a3, 0, 0, 0);
    }
    if (t >= SEQ) {  // autoregressive: x_t := h[t], add the W_ih side too
#pragma unroll
      for (int i = 0; i < 8; ++i) {
        a0 = __builtin_amdgcn_mfma_f32_16x16x32_f16(hf[i], bfx[0][i], a0, 0, 0, 0);
        a1 = __builtin_amdgcn_mfma_f32_16x16x32_f16(hf[i], bfx[1][i], a1, 0, 0, 0);
        a2 = __builtin_amdgcn_mfma_f32_16x16x32_f16(hf[i], bfx[2][i], a2, 0, 0, 0);
        a3 = __builtin_amdgcn_mfma_f32_16x16x32_f16(hf[i], bfx[3][i], a3, 0, 0, 0);
      }
    }

    // C/D layout: col = lane&15, row = q4*4 + reg. Stage partials for reduction.
#pragma unroll
    for (int r = 0; r < 4; ++r) {
      red[wave][q4 * 4 + r][     u16v] = a0[r];
      red[wave][q4 * 4 + r][16 + u16v] = a1[r];
      red[wave][q4 * 4 + r][32 + u16v] = a2[r];
      red[wave][q4 * 4 + r][48 + u16v] = a3[r];
    }
    __syncthreads();

    // Reduce 4 K-partials + bias, then LSTM cell math in fp32.
    float gi = bi, gf = bfg, gg = bg, go = bo;
#pragma unroll
    for (int w2 = 0; w2 < 4; ++w2) {
      gi += red[w2][er][     eu];
      gf += red[w2][er][16 + eu];
      gg += red[w2][er][32 + eu];
      go += red[w2][er][48 + eu];
    }
    c = fast_sigmoid(gf) * c + fast_sigmoid(gi) * fast_tanh(gg);
    float h = fast_sigmoid(go) * fast_tanh(c);
    hst[er][eu] = f2h_bits(h);
    if (t >= SEQ) out[(size_t)(t - SEQ) * BH + rge * 1024 + ub + eu] = h;
    __syncthreads();   // hst visible to wave 0

    // Publish h[t+1] slice: 512B contiguous (blocked layout), one u64 per lane,
    // then raise our flag. Release in the SAME wave orders the stores.
    if (wave == 0) {
      unsigned long long val = *(unsigned long long*)&hst[lane >> 2][(lane & 3) * 4];
      unsigned short* dst = H16 + (size_t)(t + 1) * BH
                            + ((size_t)(q * 64 + s) << 8) + lane * 4;
      __hip_atomic_store((unsigned long long*)dst, val, __ATOMIC_RELAXED, __HIP_MEMORY_SCOPE_AGENT);
      if (lane == 0)
        __hip_atomic_store(flags + q * 64 + s, t + 1,
                           __ATOMIC_RELEASE, __HIP_MEMORY_SCOPE_AGENT);
    }
  }
}

extern "C" void kernel_launch(void* const* d_in, const int* in_sizes, int n_in,
                              void* d_out, int out_size, void* d_ws, size_t ws_size,
                              hipStream_t stream) {
  const float* x    = (const float*)d_in[0];
  const float* hx0  = (const float*)d_in[1];
  const float* cx0  = (const float*)d_in[2];
  const float* W_ih = (const float*)d_in[3];
  const float* W_hh = (const float*)d_in[4];
  const float* b_ih = (const float*)d_in[5];
  const float* b_hh = (const float*)d_in[6];

  // Workspace: X16 (67.1 MB) | H16 (67.5 MB) | flags (1 KB)  ~= 135 MB
  unsigned short* X16 = (unsigned short*)d_ws;
  unsigned short* H16 = X16 + (size_t)SEQ * BH;
  int* flags = (int*)(H16 + (size_t)NBUF * BH);

  hipMemsetAsync(flags, 0, 256 * sizeof(int), stream);
  cvt_kernel<<<1024, 256, 0, stream>>>(x, hx0, X16, H16);
  lstm_kernel<<<256, 256, 0, stream>>>(cx0, W_ih, W_hh, b_ih, b_hh,
                                       X16, H16, flags, (float*)d_out);
}

// Round 4
// 3530.717 us; speedup vs baseline: 2.5739x; 1.1775x over previous
//
#include <hip/hip_runtime.h>

#define SEQ 512
#define TOT 514                 // 512 scan steps + 2 autoregressive steps
#define BH  65536               // 64 rows * 1024 hidden = elems per h/x timestep
#define NBUF (TOT + 1)          // h buffers: h[0]=hx0, h[t+1] = output of step t

typedef _Float16 f16x8 __attribute__((ext_vector_type(8)));
typedef float f32x4 __attribute__((ext_vector_type(4)));

__device__ __forceinline__ unsigned short f2h_bits(float f) {
  union { _Float16 h; unsigned short s; } u; u.h = (_Float16)f; return u.s;
}

__device__ __forceinline__ float fast_sigmoid(float x) {
  return 1.f / (1.f + __expf(-x));
}
__device__ __forceinline__ float fast_tanh(float x) {
  float e = __expf(-2.f * fabsf(x));
  float r = (1.f - e) / (1.f + e);
  return copysignf(r, x);
}

// Convert x [512,64,1024] fp32 -> f16 (row-major) and hx0 -> blocked H layout
// H[t][q][s][r:16][u:16] (each producer block's slice = 512B contiguous).
__global__ void cvt_kernel(const float* __restrict__ x, const float* __restrict__ hx0,
                           unsigned short* __restrict__ X16, unsigned short* __restrict__ H0) {
  const long long n4x = (long long)SEQ * BH / 4;
  const long long n4h = BH / 4;
  const long long stride = (long long)gridDim.x * blockDim.x;
  for (long long i = (long long)blockIdx.x * blockDim.x + threadIdx.x;
       i < n4x + n4h; i += stride) {
    const float* src; unsigned short* dst;
    if (i < n4x) {
      src = x + 4 * i; dst = X16 + 4 * i;
    } else {
      long long e = (i - n4x) * 4;         // blocked linear offset
      int u0 = e & 15, r = (e >> 4) & 15, sl = (e >> 8) & 63, qq = (int)(e >> 14);
      src = hx0 + (qq * 16 + r) * 1024 + sl * 16 + u0;
      dst = H0 + e;
    }
    float4 v = *(const float4*)src;
    union { unsigned short s[4]; unsigned long long u; } pk;
    pk.s[0] = f2h_bits(v.x); pk.s[1] = f2h_bits(v.y);
    pk.s[2] = f2h_bits(v.z); pk.s[3] = f2h_bits(v.w);
    *(unsigned long long*)dst = pk.u;
  }
}

// Persistent LSTM kernel. Grid = 256 blocks (1/CU), 256 threads (4 waves).
// block -> (batch quarter q: rows [16q,16q+16), unit slice ub = s*16).
// Wave w owns K-slice [w*256,+256) of BOTH W_ih and W_hh, register-resident.
// Sync design (no hardware acquire — relaxed agent atomics observe LLC; every
// H16 address is write-once/read-once so stale L2 lines are impossible):
//   producer: ew -> per-thread 2B agent store (coalesced 128B/wave)
//             -> __syncthreads (vmcnt drain) -> tid0 release flag store
//   consumer: per-wave spin on ITS 16 producers' flags (relaxed, no sleep)
//             -> compiler fence -> relaxed agent h loads -> MFMA
__global__ __launch_bounds__(256, 1)
void lstm_kernel(const float* __restrict__ cx0,
                 const float* __restrict__ W_ih, const float* __restrict__ W_hh,
                 const float* __restrict__ b_ih, const float* __restrict__ b_hh,
                 const unsigned short* __restrict__ X16,
                 unsigned short* __restrict__ H16,
                 int* __restrict__ flags,
                 float* __restrict__ out) {
  __shared__ float red[4][16][68];          // [wave][m][n], pad 64->68

  const int tid  = threadIdx.x;
  const int wave = tid >> 6;
  const int lane = tid & 63;
  const int u16v = lane & 15;               // MFMA m (A row) / n (B col) index
  const int q4   = lane >> 4;               // MFMA quad
  const int q    = blockIdx.x >> 6;         // batch quarter
  const int s    = blockIdx.x & 63;         // unit-slice index
  const int ub   = s * 16;                  // hidden-unit base
  const int kb   = wave * 256;              // this wave's K-slice (both matrices)

  // ---------- stage weight B-fragments into registers (fp32 -> f16) ----------
  // B layout for mfma_f32_16x16x32_f16: B[k = q4*8+j][n = lane&15]; row-major
  // W[col][k] matches k-contiguity exactly.
  f16x8 bfx[4][8], bfh[4][8];
#pragma unroll
  for (int g = 0; g < 4; ++g) {
    const float* wi = W_ih + (size_t)((g << 10) + ub + u16v) * 1024 + kb + q4 * 8;
    const float* wh = W_hh + (size_t)((g << 10) + ub + u16v) * 1024 + kb + q4 * 8;
#pragma unroll
    for (int i = 0; i < 8; ++i) {
      float4 x0 = *(const float4*)(wi + i * 32);
      float4 x1 = *(const float4*)(wi + i * 32 + 4);
      float4 h0 = *(const float4*)(wh + i * 32);
      float4 h1 = *(const float4*)(wh + i * 32 + 4);
      f16x8 bx, bh;
      bx[0] = (_Float16)x0.x; bx[1] = (_Float16)x0.y; bx[2] = (_Float16)x0.z; bx[3] = (_Float16)x0.w;
      bx[4] = (_Float16)x1.x; bx[5] = (_Float16)x1.y; bx[6] = (_Float16)x1.z; bx[7] = (_Float16)x1.w;
      bh[0] = (_Float16)h0.x; bh[1] = (_Float16)h0.y; bh[2] = (_Float16)h0.z; bh[3] = (_Float16)h0.w;
      bh[4] = (_Float16)h1.x; bh[5] = (_Float16)h1.y; bh[6] = (_Float16)h1.z; bh[7] = (_Float16)h1.w;
      bfx[g][i] = bx; bfh[g][i] = bh;
    }
  }

  // ---------- per-thread recurrent state (elementwise mapping) ----------
  const int er = tid >> 4, eu = tid & 15;   // (row-in-quarter, unit-in-slice)
  const int rge = q * 16 + er;              // global batch row
  float c = cx0[rge * 1024 + ub + eu];
  const float bi  = b_ih[       ub + eu] + b_hh[       ub + eu];
  const float bfg = b_ih[1024 + ub + eu] + b_hh[1024 + ub + eu];
  const float bg  = b_ih[2048 + ub + eu] + b_hh[2048 + ub + eu];
  const float bo  = b_ih[3072 + ub + eu] + b_hh[3072 + ub + eu];

  // x A-fragment base (row-major [64,1024] f16): A[m=lane&15][k=q4*8+j]
  const size_t xbase = (size_t)(q * 16 + u16v) * 1024 + kb + q4 * 8;
  // h A-fragment base (blocked layout): element offset within a timestep
  const size_t hfrag = ((size_t)(q * 64 + wave * 16 + (q4 >> 1)) << 8)
                       + u16v * 16 + (q4 & 1) * 8;     // + i*512 per k-iter
  // this wave's 16 producers' flags (replicated 4x across the wave)
  const int* fpoll = flags + q * 64 + wave * 16 + u16v;
  // this block's publish address offset within a timestep (contiguous per wave)
  const size_t puboff = ((size_t)(q * 64 + s) << 8) + tid;

  for (int t = 0; t < TOT; ++t) {
    f32x4 a0 = {0.f, 0.f, 0.f, 0.f}, a1 = a0, a2 = a0, a3 = a0;

    // ===== x-phase: no dependency on h[t]; issued before the poll =====
    if (t < SEQ) {
      const unsigned short* xs = X16 + (size_t)t * BH + xbase;
      f16x8 xf[8];
#pragma unroll
      for (int i = 0; i < 8; ++i) xf[i] = *(const f16x8*)(xs + i * 32);
#pragma unroll
      for (int i = 0; i < 8; ++i) {
        a0 = __builtin_amdgcn_mfma_f32_16x16x32_f16(xf[i], bfx[0][i], a0, 0, 0, 0);
        a1 = __builtin_amdgcn_mfma_f32_16x16x32_f16(xf[i], bfx[1][i], a1, 0, 0, 0);
        a2 = __builtin_amdgcn_mfma_f32_16x16x32_f16(xf[i], bfx[2][i], a2, 0, 0, 0);
        a3 = __builtin_amdgcn_mfma_f32_16x16x32_f16(xf[i], bfx[3][i], a3, 0, 0, 0);
      }
    }

    // ===== per-wave wait: only OUR 16 producers need to have published =====
    while (true) {
      int v = __hip_atomic_load(fpoll, __ATOMIC_RELAXED, __HIP_MEMORY_SCOPE_AGENT);
      if (__all(v >= t)) break;
    }
    __atomic_signal_fence(__ATOMIC_ACQUIRE);   // compiler-only; no buffer_inv

    // ===== h-phase: relaxed agent loads (LLC-coherent, write-once buffers) =====
    const unsigned short* hs = H16 + (size_t)t * BH + hfrag;
    f16x8 hf[8];
#pragma unroll
    for (int i = 0; i < 8; ++i) {
      const unsigned short* p = hs + i * 512;
      union { unsigned long long u[2]; f16x8 v; } cv;
      cv.u[0] = __hip_atomic_load((unsigned long long*)p,       __ATOMIC_RELAXED, __HIP_MEMORY_SCOPE_AGENT);
      cv.u[1] = __hip_atomic_load((unsigned long long*)(p + 4), __ATOMIC_RELAXED, __HIP_MEMORY_SCOPE_AGENT);
      hf[i] = cv.v;
    }
#pragma unroll
    for (int i = 0; i < 8; ++i) {
      a0 = __builtin_amdgcn_mfma_f32_16x16x32_f16(hf[i], bfh[0][i], a0, 0, 0, 0);
      a1 = __builtin_amdgcn_mfma_f32_16x16x32_f16(hf[i], bfh[1][i], a1, 0, 0, 0);
      a2 = __builtin_amdgcn_mfma_f32_16x16x32_f16(hf[i], bfh[2][i], a2, 0, 0, 0);
      a3 = __builtin_amdgcn_mfma_f32_16x16x32_f16(hf[i], bfh[3][i], a3, 0, 0, 0);
    }
    if (t >= SEQ) {  // autoregressive: x_t := h[t], add the W_ih side too
#pragma unroll
      for (int i = 0; i < 8; ++i) {
        a0 = __builtin_amdgcn_mfma_f32_16x16x32_f16(hf[i], bfx[0][i], a0, 0, 0, 0);
        a1 = __builtin_amdgcn_mfma_f32_16x16x32_f16(hf[i], bfx[1][i], a1, 0, 0, 0);
        a2 = __builtin_amdgcn_mfma_f32_16x16x32_f16(hf[i], bfx[2][i], a2, 0, 0, 0);
        a3 = __builtin_amdgcn_mfma_f32_16x16x32_f16(hf[i], bfx[3][i], a3, 0, 0, 0);
      }
    }

    // C/D layout: col = lane&15, row = q4*4 + reg. Stage partials for reduction.
#pragma unroll
    for (int r = 0; r < 4; ++r) {
      red[wave][q4 * 4 + r][     u16v] = a0[r];
      red[wave][q4 * 4 + r][16 + u16v] = a1[r];
      red[wave][q4 * 4 + r][32 + u16v] = a2[r];
      red[wave][q4 * 4 + r][48 + u16v] = a3[r];
    }
    __syncthreads();

    // Reduce 4 K-partials + bias, then LSTM cell math in fp32.
    float gi = bi, gf = bfg, gg = bg, go = bo;
#pragma unroll
    for (int w2 = 0; w2 < 4; ++w2) {
      gi += red[w2][er][     eu];
      gf += red[w2][er][16 + eu];
      gg += red[w2][er][32 + eu];
      go += red[w2][er][48 + eu];
    }
    c = fast_sigmoid(gf) * c + fast_sigmoid(gi) * fast_tanh(gg);
    float h = fast_sigmoid(go) * fast_tanh(c);

    // Publish h[t+1]: per-thread 2B agent store, contiguous 128B per wave.
    __hip_atomic_store(H16 + (size_t)(t + 1) * BH + puboff, f2h_bits(h),
                       __ATOMIC_RELAXED, __HIP_MEMORY_SCOPE_AGENT);
    if (t >= SEQ) out[(size_t)(t - SEQ) * BH + rge * 1024 + ub + eu] = h;
    __syncthreads();   // drains vmcnt in ALL waves -> stores visible at LLC
    if (tid == 0)
      __hip_atomic_store(flags + q * 64 + s, t + 1,
                         __ATOMIC_RELEASE, __HIP_MEMORY_SCOPE_AGENT);
  }
}

extern "C" void kernel_launch(void* const* d_in, const int* in_sizes, int n_in,
                              void* d_out, int out_size, void* d_ws, size_t ws_size,
                              hipStream_t stream) {
  const float* x    = (const float*)d_in[0];
  const float* hx0  = (const float*)d_in[1];
  const float* cx0  = (const float*)d_in[2];
  const float* W_ih = (const float*)d_in[3];
  const float* W_hh = (const float*)d_in[4];
  const float* b_ih = (const float*)d_in[5];
  const float* b_hh = (const float*)d_in[6];

  // Workspace: X16 (67.1 MB) | H16 (67.5 MB) | flags (1 KB)  ~= 135 MB
  unsigned short* X16 = (unsigned short*)d_ws;
  unsigned short* H16 = X16 + (size_t)SEQ * BH;
  int* flags = (int*)(H16 + (size_t)NBUF * BH);

  hipMemsetAsync(flags, 0, 256 * sizeof(int), stream);
  cvt_kernel<<<1024, 256, 0, stream>>>(x, hx0, X16, H16);
  lstm_kernel<<<256, 256, 0, stream>>>(cx0, W_ih, W_hh, b_ih, b_hh,
                                       X16, H16, flags, (float*)d_out);
}

// Round 5
// 1994.229 us; speedup vs baseline: 4.5571x; 1.7705x over previous
//
#include <hip/hip_runtime.h>

#define SEQ 512
#define TOT 514                 // 512 scan steps + 2 autoregressive steps
#define BH  65536               // 64 rows * 1024 hidden = elems per h/x timestep
#define NBUF (TOT + 1)          // h buffers: h[0]=hx0, h[t+1] = output of step t

typedef _Float16 f16x8 __attribute__((ext_vector_type(8)));
typedef float f32x4 __attribute__((ext_vector_type(4)));

__device__ __forceinline__ unsigned short f2h_bits(float f) {
  union { _Float16 h; unsigned short s; } u; u.h = (_Float16)f; return u.s;
}

__device__ __forceinline__ float fast_sigmoid(float x) {
  return 1.f / (1.f + __expf(-x));
}
__device__ __forceinline__ float fast_tanh(float x) {
  float e = __expf(-2.f * fabsf(x));
  float r = (1.f - e) / (1.f + e);
  return copysignf(r, x);
}

// SWAR: nonzero iff any 16-bit halfword of u equals 0xFFFF (the sentinel).
// |h|<1 strictly, so published f16 values can never be 0xFFFF (-NaN).
__device__ __forceinline__ unsigned long long dirty16(unsigned long long u) {
  unsigned long long n = ~u;   // sentinel halfword -> 0x0000
  return (n - 0x0001000100010001ULL) & ~n & 0x8000800080008000ULL;
}

// Convert x [512,64,1024] fp32 -> f16 (row-major) and hx0 -> blocked H layout
// H[t][q][s][r:16][u:16] (each producer block's slice = 512B contiguous).
__global__ void cvt_kernel(const float* __restrict__ x, const float* __restrict__ hx0,
                           unsigned short* __restrict__ X16, unsigned short* __restrict__ H0) {
  const long long n4x = (long long)SEQ * BH / 4;
  const long long n4h = BH / 4;
  const long long stride = (long long)gridDim.x * blockDim.x;
  for (long long i = (long long)blockIdx.x * blockDim.x + threadIdx.x;
       i < n4x + n4h; i += stride) {
    const float* src; unsigned short* dst;
    if (i < n4x) {
      src = x + 4 * i; dst = X16 + 4 * i;
    } else {
      long long e = (i - n4x) * 4;         // blocked linear offset
      int u0 = e & 15, r = (e >> 4) & 15, sl = (e >> 8) & 63, qq = (int)(e >> 14);
      src = hx0 + (qq * 16 + r) * 1024 + sl * 16 + u0;
      dst = H0 + e;
    }
    float4 v = *(const float4*)src;
    union { unsigned short s[4]; unsigned long long u; } pk;
    pk.s[0] = f2h_bits(v.x); pk.s[1] = f2h_bits(v.y);
    pk.s[2] = f2h_bits(v.z); pk.s[3] = f2h_bits(v.w);
    *(unsigned long long*)dst = pk.u;
  }
}

// Persistent LSTM kernel. Grid = 256 blocks (1/CU), 256 threads (4 waves).
// block -> (batch quarter q: rows [16q,16q+16), unit slice ub = s*16).
// Wave w owns K-slice [w*256,+256) of BOTH W_ih and W_hh, register-resident.
// Sync design: NO flags. H16 is pre-filled with 0xFF; producers publish h via
// relaxed agent (write-through-to-LLC) 2B stores; consumers poll the data
// words themselves until no 0xFFFF halfword remains. One LLC transit per step
// on the critical path instead of ~4 (publish-drain, flag store, flag poll,
// data load). Single __syncthreads per step via parity-double-buffered LDS.
__global__ __launch_bounds__(256, 1)
void lstm_kernel(const float* __restrict__ cx0,
                 const float* __restrict__ W_ih, const float* __restrict__ W_hh,
                 const float* __restrict__ b_ih, const float* __restrict__ b_hh,
                 const unsigned short* __restrict__ X16,
                 unsigned short* __restrict__ H16,
                 float* __restrict__ out) {
  __shared__ float red[2][4][16][68];       // [parity][wave][m][n], pad 64->68

  const int tid  = threadIdx.x;
  const int wave = tid >> 6;
  const int lane = tid & 63;
  const int u16v = lane & 15;               // MFMA m (A row) / n (B col) index
  const int q4   = lane >> 4;               // MFMA quad
  const int q    = blockIdx.x >> 6;         // batch quarter
  const int s    = blockIdx.x & 63;         // unit-slice index
  const int ub   = s * 16;                  // hidden-unit base
  const int kb   = wave * 256;              // this wave's K-slice (both matrices)

  // ---------- stage weight B-fragments into registers (fp32 -> f16) ----------
  // B layout for mfma_f32_16x16x32_f16: B[k = q4*8+j][n = lane&15]; row-major
  // W[col][k] matches k-contiguity exactly.
  f16x8 bfx[4][8], bfh[4][8];
#pragma unroll
  for (int g = 0; g < 4; ++g) {
    const float* wi = W_ih + (size_t)((g << 10) + ub + u16v) * 1024 + kb + q4 * 8;
    const float* wh = W_hh + (size_t)((g << 10) + ub + u16v) * 1024 + kb + q4 * 8;
#pragma unroll
    for (int i = 0; i < 8; ++i) {
      float4 x0 = *(const float4*)(wi + i * 32);
      float4 x1 = *(const float4*)(wi + i * 32 + 4);
      float4 h0 = *(const float4*)(wh + i * 32);
      float4 h1 = *(const float4*)(wh + i * 32 + 4);
      f16x8 bx, bh;
      bx[0] = (_Float16)x0.x; bx[1] = (_Float16)x0.y; bx[2] = (_Float16)x0.z; bx[3] = (_Float16)x0.w;
      bx[4] = (_Float16)x1.x; bx[5] = (_Float16)x1.y; bx[6] = (_Float16)x1.z; bx[7] = (_Float16)x1.w;
      bh[0] = (_Float16)h0.x; bh[1] = (_Float16)h0.y; bh[2] = (_Float16)h0.z; bh[3] = (_Float16)h0.w;
      bh[4] = (_Float16)h1.x; bh[5] = (_Float16)h1.y; bh[6] = (_Float16)h1.z; bh[7] = (_Float16)h1.w;
      bfx[g][i] = bx; bfh[g][i] = bh;
    }
  }

  // ---------- per-thread recurrent state (elementwise mapping) ----------
  const int er = tid >> 4, eu = tid & 15;   // (row-in-quarter, unit-in-slice)
  const int rge = q * 16 + er;              // global batch row
  float c = cx0[rge * 1024 + ub + eu];
  const float bi  = b_ih[       ub + eu] + b_hh[       ub + eu];
  const float bfg = b_ih[1024 + ub + eu] + b_hh[1024 + ub + eu];
  const float bg  = b_ih[2048 + ub + eu] + b_hh[2048 + ub + eu];
  const float bo  = b_ih[3072 + ub + eu] + b_hh[3072 + ub + eu];

  // x A-fragment base (row-major [64,1024] f16): A[m=lane&15][k=q4*8+j]
  const size_t xbase = (size_t)(q * 16 + u16v) * 1024 + kb + q4 * 8;
  // h A-fragment base (blocked layout): element offset within a timestep
  const size_t hfrag = ((size_t)(q * 64 + wave * 16 + (q4 >> 1)) << 8)
                       + u16v * 16 + (q4 & 1) * 8;     // + i*512 per k-iter
  // this block's publish offset within a timestep (contiguous per block)
  const size_t puboff = ((size_t)(q * 64 + s) << 8) + tid;

  for (int t = 0; t < TOT; ++t) {
    f32x4 a0 = {0.f, 0.f, 0.f, 0.f}, a1 = a0, a2 = a0, a3 = a0;

    // ===== x-phase: no dependency on h[t]; overlaps producers' publish =====
    if (t < SEQ) {
      const unsigned short* xs = X16 + (size_t)t * BH + xbase;
      f16x8 xf[8];
#pragma unroll
      for (int i = 0; i < 8; ++i) xf[i] = *(const f16x8*)(xs + i * 32);
#pragma unroll
      for (int i = 0; i < 8; ++i) {
        a0 = __builtin_amdgcn_mfma_f32_16x16x32_f16(xf[i], bfx[0][i], a0, 0, 0, 0);
        a1 = __builtin_amdgcn_mfma_f32_16x16x32_f16(xf[i], bfx[1][i], a1, 0, 0, 0);
        a2 = __builtin_amdgcn_mfma_f32_16x16x32_f16(xf[i], bfx[2][i], a2, 0, 0, 0);
        a3 = __builtin_amdgcn_mfma_f32_16x16x32_f16(xf[i], bfx[3][i], a3, 0, 0, 0);
      }
    }

    // ===== h-phase: poll the DATA until no sentinel halfword remains =====
    const unsigned short* hs = H16 + (size_t)t * BH + hfrag;
    union { unsigned long long u[2]; f16x8 v; } cv[8];
    while (true) {
#pragma unroll
      for (int i = 0; i < 8; ++i) {
        const unsigned short* p = hs + i * 512;
        cv[i].u[0] = __hip_atomic_load((const unsigned long long*)p,
                                       __ATOMIC_RELAXED, __HIP_MEMORY_SCOPE_AGENT);
        cv[i].u[1] = __hip_atomic_load((const unsigned long long*)(p + 4),
                                       __ATOMIC_RELAXED, __HIP_MEMORY_SCOPE_AGENT);
      }
      unsigned long long agg = 0;
#pragma unroll
      for (int i = 0; i < 8; ++i)
        agg |= dirty16(cv[i].u[0]) | dirty16(cv[i].u[1]);
      if (__all(agg == 0)) break;
    }

    f16x8 hf[8];
#pragma unroll
    for (int i = 0; i < 8; ++i) hf[i] = cv[i].v;
#pragma unroll
    for (int i = 0; i < 8; ++i) {
      a0 = __builtin_amdgcn_mfma_f32_16x16x32_f16(hf[i], bfh[0][i], a0, 0, 0, 0);
      a1 = __builtin_amdgcn_mfma_f32_16x16x32_f16(hf[i], bfh[1][i], a1, 0, 0, 0);
      a2 = __builtin_amdgcn_mfma_f32_16x16x32_f16(hf[i], bfh[2][i], a2, 0, 0, 0);
      a3 = __builtin_amdgcn_mfma_f32_16x16x32_f16(hf[i], bfh[3][i], a3, 0, 0, 0);
    }
    if (t >= SEQ) {  // autoregressive: x_t := h[t], add the W_ih side too
#pragma unroll
      for (int i = 0; i < 8; ++i) {
        a0 = __builtin_amdgcn_mfma_f32_16x16x32_f16(hf[i], bfx[0][i], a0, 0, 0, 0);
        a1 = __builtin_amdgcn_mfma_f32_16x16x32_f16(hf[i], bfx[1][i], a1, 0, 0, 0);
        a2 = __builtin_amdgcn_mfma_f32_16x16x32_f16(hf[i], bfx[2][i], a2, 0, 0, 0);
        a3 = __builtin_amdgcn_mfma_f32_16x16x32_f16(hf[i], bfx[3][i], a3, 0, 0, 0);
      }
    }

    // C/D layout: col = lane&15, row = q4*4 + reg. Stage partials (parity buf).
    const int par = t & 1;
#pragma unroll
    for (int r = 0; r < 4; ++r) {
      red[par][wave][q4 * 4 + r][     u16v] = a0[r];
      red[par][wave][q4 * 4 + r][16 + u16v] = a1[r];
      red[par][wave][q4 * 4 + r][32 + u16v] = a2[r];
      red[par][wave][q4 * 4 + r][48 + u16v] = a3[r];
    }
    __syncthreads();   // the ONLY barrier per step (parity buffer removes WAR)

    // Reduce 4 K-partials + bias, then LSTM cell math in fp32.
    float gi = bi, gf = bfg, gg = bg, go = bo;
#pragma unroll
    for (int w2 = 0; w2 < 4; ++w2) {
      gi += red[par][w2][er][     eu];
      gf += red[par][w2][er][16 + eu];
      gg += red[par][w2][er][32 + eu];
      go += red[par][w2][er][48 + eu];
    }
    c = fast_sigmoid(gf) * c + fast_sigmoid(gi) * fast_tanh(gg);
    float h = fast_sigmoid(go) * fast_tanh(c);

    // Publish h[t+1]: per-thread 2B agent store (write-through to LLC).
    // The data IS the flag: consumers detect non-sentinel halfwords.
    __hip_atomic_store(H16 + (size_t)(t + 1) * BH + puboff, f2h_bits(h),
                       __ATOMIC_RELAXED, __HIP_MEMORY_SCOPE_AGENT);
    if (t >= SEQ) out[(size_t)(t - SEQ) * BH + rge * 1024 + ub + eu] = h;
  }
}

extern "C" void kernel_launch(void* const* d_in, const int* in_sizes, int n_in,
                              void* d_out, int out_size, void* d_ws, size_t ws_size,
                              hipStream_t stream) {
  const float* x    = (const float*)d_in[0];
  const float* hx0  = (const float*)d_in[1];
  const float* cx0  = (const float*)d_in[2];
  const float* W_ih = (const float*)d_in[3];
  const float* W_hh = (const float*)d_in[4];
  const float* b_ih = (const float*)d_in[5];
  const float* b_hh = (const float*)d_in[6];

  // Workspace: X16 (67.1 MB) | H16 (67.5 MB)  ~= 135 MB
  unsigned short* X16 = (unsigned short*)d_ws;
  unsigned short* H16 = X16 + (size_t)SEQ * BH;

  // Sentinel-fill H16 (0xFFFF halfwords), then cvt overwrites H[0] with hx0.
  hipMemsetAsync(H16, 0xFF, (size_t)NBUF * BH * sizeof(unsigned short), stream);
  cvt_kernel<<<1024, 256, 0, stream>>>(x, hx0, X16, H16);
  lstm_kernel<<<256, 256, 0, stream>>>(cx0, W_ih, W_hh, b_ih, b_hh,
                                       X16, H16, (float*)d_out);
}